// Round 15
// baseline (474.249 us; speedup 1.0000x reference)
//
#include <hip/hip_runtime.h>
#include <hip/hip_bf16.h>
#include <stdint.h>

// MoE FFN: B=2,T=2048,D=1024,F=4096,E=8,K=2. S=4096 tokens, 8192 assignments.
#define S_TOK 4096
#define DDIM  1024
#define FDIM  4096
#define EEXP  8
#define PCAP  9216              // arena padded to 128 per expert (8192 + 8*128 max)
#define BUF   24576

typedef __bf16 bf16x8 __attribute__((ext_vector_type(8)));
typedef __bf16 bf16x4 __attribute__((ext_vector_type(4)));
typedef float  f32x4  __attribute__((ext_vector_type(4)));

__device__ __forceinline__ unsigned short f2bf(float f) {
    union { float f; unsigned u; } v; v.f = f;
    unsigned u = v.u;
    return (unsigned short)((u + 0x7FFFu + ((u >> 16) & 1u)) >> 16);  // RNE
}

// global -> LDS async copy, 16B/lane. Offset arg MUST stay 0 (r8 lesson).
__device__ __forceinline__ void gload16(const void* g, void* l) {
    auto gp = reinterpret_cast<const __attribute__((address_space(1))) uint32_t*>(
        reinterpret_cast<uintptr_t>(g));
    auto lp = reinterpret_cast<__attribute__((address_space(3))) uint32_t*>(
        static_cast<uint32_t>(reinterpret_cast<uintptr_t>(l)));
    __builtin_amdgcn_global_load_lds(gp, lp, 16, 0, 0);
}

// ---------------- small kernels ----------------

__global__ void zero_k(int* p, int n) {
    int i = threadIdx.x;
    if (i < n) p[i] = 0;
}

// w1 (E,F,D) fp32 -> packed bf16 [e][ntile=f>>8][kt=d>>5][row=f&255][chunk: d&31]
__global__ void cvt_w1_packed(const float* __restrict__ src, char* __restrict__ dst) {
    int stride = gridDim.x * blockDim.x;
    int total = EEXP * FDIM * DDIM / 4;
    for (int i = blockIdx.x * blockDim.x + threadIdx.x; i < total; i += stride) {
        int b0 = i << 2;
        int d = b0 & 1023;
        int f = (b0 >> 10) & 4095;
        int e = b0 >> 22;
        float4 v = ((const float4*)src)[i];
        bf16x4 o = { (__bf16)v.x, (__bf16)v.y, (__bf16)v.z, (__bf16)v.w };
        size_t off = (((size_t)((e * 16 + (f >> 8)) * 32 + (d >> 5))) * 256 + (f & 255)) * 64 + (d & 31) * 2;
        *(bf16x4*)(dst + off) = o;
    }
}

// w2 (E,D,F) fp32 -> packed bf16 [e][ntile=n>>8][kt=k>>5][row=n&255][chunk: k&31]
__global__ void cvt_w2_packed(const float* __restrict__ src, char* __restrict__ dst) {
    int stride = gridDim.x * blockDim.x;
    int total = EEXP * DDIM * FDIM / 4;
    for (int i = blockIdx.x * blockDim.x + threadIdx.x; i < total; i += stride) {
        int b0 = i << 2;
        int k = b0 & 4095;
        int n = (b0 >> 12) & 1023;
        int e = b0 >> 22;
        float4 v = ((const float4*)src)[i];
        bf16x4 o = { (__bf16)v.x, (__bf16)v.y, (__bf16)v.z, (__bf16)v.w };
        size_t off = (((size_t)((e * 4 + (n >> 8)) * 128 + (k >> 5))) * 256 + (n & 255)) * 64 + (k & 31) * 2;
        *(bf16x4*)(dst + off) = o;
    }
}

// Router: one wave per token, fp32 (must match numpy top-2 selection). Fused x->bf16.
__global__ void router_k(const float* __restrict__ x, const float* __restrict__ gw,
                         unsigned short* __restrict__ xb,
                         int* __restrict__ topk_e, float* __restrict__ topk_g,
                         int* __restrict__ counts) {
    int s = blockIdx.x;
    int l = threadIdx.x;
    const float* xr = x + (size_t)s * DDIM;
    unsigned short* xbr = xb + (size_t)s * DDIM;
    float acc[EEXP];
#pragma unroll
    for (int e = 0; e < EEXP; ++e) acc[e] = 0.f;
    for (int i = 0; i < DDIM; i += 64) {
        float xv = xr[i + l];
        xbr[i + l] = f2bf(xv);
#pragma unroll
        for (int e = 0; e < EEXP; ++e) acc[e] = fmaf(xv, gw[e * DDIM + i + l], acc[e]);
    }
#pragma unroll
    for (int e = 0; e < EEXP; ++e)
        for (int off = 32; off > 0; off >>= 1) acc[e] += __shfl_down(acc[e], off, 64);
    if (l == 0) {
        float v0 = -1e30f, v1 = -1e30f; int i0 = 0, i1 = 0;
#pragma unroll
        for (int e = 0; e < EEXP; ++e) {
            float v = acc[e];
            if (v > v0)      { v1 = v0; i1 = i0; v0 = v; i0 = e; }
            else if (v > v1) { v1 = v;  i1 = e; }
        }
        float t = expf(v1 - v0);
        float d = 1.f + t;
        topk_e[2 * s] = i0; topk_e[2 * s + 1] = i1;
        topk_g[2 * s] = 1.f / d; topk_g[2 * s + 1] = t / d;
        atomicAdd(&counts[i0], 1);
        atomicAdd(&counts[i1], 1);
    }
}

// Padded scan: basep[e] 128-aligned cumsum of padded counts.
__global__ void scan_k(const int* __restrict__ counts, int* __restrict__ basep) {
    if (threadIdx.x == 0) {
        int b = 0;
        for (int e = 0; e < EEXP; ++e) {
            basep[e] = b;
            b += (counts[e] + 127) & ~127;
        }
        basep[EEXP] = b;   // padded total
    }
}

__global__ void scatter_k(const int* __restrict__ topk_e, int* __restrict__ rankctr,
                          const int* __restrict__ basep, int* __restrict__ arena_token,
                          int* __restrict__ pos_of) {
    int s = blockIdx.x * blockDim.x + threadIdx.x;
    if (s >= S_TOK) return;
#pragma unroll
    for (int t = 0; t < 2; ++t) {
        int e = topk_e[2 * s + t];
        int r = atomicAdd(&rankctr[e], 1);
        int p = basep[e] + r;
        arena_token[p] = s;
        pos_of[2 * s + t] = p;
    }
}

// Gather x into packed A arena: xg[tile=p>>7][kt=d>>5][row=p&127][chunk: d&31].
// One thread per 16B (8 elems). Pad rows duplicate the segment's last token.
__global__ void gather_k(const unsigned short* __restrict__ xb, const int* __restrict__ arena_token,
                         const int* __restrict__ counts, const int* __restrict__ basep,
                         char* __restrict__ xg) {
    int gid = blockIdx.x * blockDim.x + threadIdx.x;   // PCAP*128 threads
    int p = gid >> 7;
    int d0 = (gid & 127) * 8;
    if (p >= basep[EEXP]) return;
    int e = 0;
#pragma unroll
    for (int i = 1; i < EEXP; ++i) if (p >= basep[i]) e = i;
    int cnt = counts[e];
    int r = p - basep[e];
    int tok = (cnt > 0) ? arena_token[basep[e] + ((r < cnt) ? r : (cnt - 1))] : 0;
    // 16B read from xb, 16B write to packed xg
    const char* s = (const char*)(xb + (size_t)tok * DDIM + d0);
    size_t off = ((size_t)(p >> 7) * 32 + (d0 >> 5)) * 8192 + (p & 127) * 64 + (d0 & 31) * 2;
    *(float4*)(xg + off) = *(const float4*)s;
}

// ---------------- MFMA GEMM: BM=128 x BN=256, BK=32, 8 waves, triple-buffer lookahead-2 ----
// r15: PACKED operands — every gload16 reads a CONTIGUOUS 1KB/wave (8 sequential cache
// lines) instead of 16 scattered 64B row-slices. Theory: staging was fragment-issue-bound
// (~6.4 cyc/64B-frag observed vs ~3 for the verified contiguous kernels). Pipeline,
// geometry, LDS image, fragment reads = r13/r14 byte-identical (linear image accepted;
// compute path proven ~10us by r10 ablation).
// Asrc: packed A [tile][kt][128][64B]; Bw: packed B [(e*ntiles+n)][kt][256][64B].
template <int EPI>
__global__ __launch_bounds__(512, 4) void moe_gemm(
    const char* __restrict__ Asrc, const char* __restrict__ Bw,
    const float* __restrict__ bias, char* __restrict__ hOutP,
    float* __restrict__ fOut, const int* __restrict__ counts,
    const int* __restrict__ basep, int ktiles, int Nd, int ntiles, int ny) {
    int cpx = gridDim.x >> 3;
    int bid = blockIdx.x;
    int wid = (bid & 7) * cpx + (bid >> 3);
    int my  = wid % ny;
    int q   = wid / ny;
    int e   = q % EEXP;
    int n   = q / EEXP;

    int count = counts[e];
    int m0 = my * 128;
    if (m0 >= count) return;
    int base = basep[e];          // 128-aligned
    int n0 = n * 256;
    int tid = threadIdx.x, w = tid >> 6, l = tid & 63;

    __shared__ __align__(16) char smem[3 * BUF];

    // ---- packed stage pointers: contiguous 1KB per wave-instruction ----
    int mtileG = (base >> 7) + my;
    const char* pA = Asrc + (size_t)mtileG * ktiles * 8192 + tid * 16;
    const char* pB = Bw + (size_t)(e * ntiles + n) * ktiles * 16384 + tid * 16;

#define STG(sb) do {                                                   \
        char* d_ = smem + (sb) * BUF;                                  \
        gload16(pA, d_ + w * 1024);                                    \
        gload16(pB, d_ + 8192 + w * 1024);                             \
        gload16(pB + 8192, d_ + 16384 + w * 1024);                     \
        pA += 8192; pB += 16384;                                       \
    } while (0)

    // ---- fragment read addressing (linear image; conflicts hidden per r10 ablation) ----
    int wm = w >> 2, wn = w & 3;                 // 2(M) x 4(N) waves, wave tile 64x64
    int hi = l >> 4;
    int rdc = hi << 4;
    const char* Ar = smem + (size_t)(wm * 64 + (l & 15)) * 64 + rdc;
    const char* Br = smem + 8192 + (size_t)(wn * 64 + (l & 15)) * 64 + rdc;

    f32x4 acc[4][4];
#pragma unroll
    for (int i = 0; i < 4; ++i)
#pragma unroll
        for (int j = 0; j < 4; ++j) acc[i][j] = (f32x4){0.f, 0.f, 0.f, 0.f};

    int nt = ktiles;
    // prologue: lookahead-2 — tiles 0,1 into slots 0,1.
    STG(0); STG(1);
    asm volatile("s_waitcnt vmcnt(3)" ::: "memory");   // tile0 landed; tile1 in flight
    __builtin_amdgcn_sched_barrier(0);
    __builtin_amdgcn_s_barrier();
    asm volatile("" ::: "memory");

    int cs = 0, ss = 2;   // consume slot t%3; stage tile t+2 into slot (t+2)%3
    for (int t = 0; t < nt; ++t) {
        bool pre = (t + 2 < nt);
        if (pre) STG(ss);
        const char* Ab = Ar + cs * BUF;
        const char* Bb = Br + cs * BUF;
        bf16x8 bq[4];
#pragma unroll
        for (int ni = 0; ni < 4; ++ni) bq[ni] = *(const bf16x8*)(Bb + ni * 1024);
#pragma unroll
        for (int mi = 0; mi < 4; ++mi) {
            bf16x8 a = *(const bf16x8*)(Ab + mi * 1024);
#pragma unroll
            for (int ni = 0; ni < 4; ++ni)
                acc[mi][ni] = __builtin_amdgcn_mfma_f32_16x16x32_bf16(a, bq[ni], acc[mi][ni], 0, 0, 0);
        }
        if (pre) asm volatile("s_waitcnt vmcnt(3)" ::: "memory");  // t+1 landed; t+2 floats
        else     asm volatile("s_waitcnt vmcnt(0)" ::: "memory");  // tail drain
        __builtin_amdgcn_sched_barrier(0);
        __builtin_amdgcn_s_barrier();
        asm volatile("" ::: "memory");
        cs = (cs == 2) ? 0 : cs + 1;
        ss = (ss == 2) ? 0 : ss + 1;
    }
#undef STG

    // Epilogue. C/D layout: col = lane&15, row = (lane>>4)*4 + reg  [m89 verified]
#pragma unroll
    for (int mi = 0; mi < 4; ++mi)
#pragma unroll
        for (int ni = 0; ni < 4; ++ni)
#pragma unroll
            for (int r = 0; r < 4; ++r) {
                int rl = wm * 64 + mi * 16 + hi * 4 + r;
                int gr = m0 + rl;
                if (gr < count) {
                    int col = n0 + wn * 64 + ni * 16 + (l & 15);
                    float v = acc[mi][ni][r];
                    if (EPI == 1) {
                        v += bias[e * Nd + col];
                        v = fmaxf(v, 0.f);
                        // write hA in G2-packed A layout: [tile][kt(128)][row][chunk]
                        int prow = base + gr;
                        size_t off = ((size_t)(prow >> 7) * 128 + (col >> 5)) * 8192
                                   + (prow & 127) * 64 + (col & 31) * 2;
                        *(unsigned short*)(hOutP + off) = f2bf(v);
                    } else {
                        fOut[(size_t)(base + gr) * Nd + col] = v;
                    }
                }
            }
}

// Deterministic combine (single partial): y = g0*(outP[p0]+b2[e0]) + g1*(outP[p1]+b2[e1])
__global__ void combine_k(const float* __restrict__ outP, const float* __restrict__ b2,
                          const int* __restrict__ topk_e, const float* __restrict__ topk_g,
                          const int* __restrict__ pos_of, float* __restrict__ y) {
    int idx = blockIdx.x * blockDim.x + threadIdx.x;
    int s = idx >> 8;
    int c = (idx & 255) * 4;
    int e0 = topk_e[2 * s], e1 = topk_e[2 * s + 1];
    float g0 = topk_g[2 * s], g1 = topk_g[2 * s + 1];
    int p0 = pos_of[2 * s], p1 = pos_of[2 * s + 1];
    float4 a0 = *(const float4*)(outP + (size_t)p0 * DDIM + c);
    float4 b0v = *(const float4*)(outP + (size_t)p1 * DDIM + c);
    float4 c0 = *(const float4*)(b2 + (size_t)e0 * DDIM + c);
    float4 c1 = *(const float4*)(b2 + (size_t)e1 * DDIM + c);
    float4 r;
    r.x = g0 * (a0.x + c0.x) + g1 * (b0v.x + c1.x);
    r.y = g0 * (a0.y + c0.y) + g1 * (b0v.y + c1.y);
    r.z = g0 * (a0.z + c0.z) + g1 * (b0v.z + c1.z);
    r.w = g0 * (a0.w + c0.w) + g1 * (b0v.w + c1.w);
    *(float4*)(y + (size_t)s * DDIM + c) = r;
}

extern "C" void kernel_launch(void* const* d_in, const int* in_sizes, int n_in,
                              void* d_out, int out_size, void* d_ws, size_t ws_size,
                              hipStream_t stream) {
    const float* x      = (const float*)d_in[0];
    const float* gate_w = (const float*)d_in[1];
    const float* w1     = (const float*)d_in[2];
    const float* b1     = (const float*)d_in[3];
    const float* w2     = (const float*)d_in[4];
    const float* b2     = (const float*)d_in[5];

    char* p = (char*)d_ws;
    char* w1bp = p;                         // 64 MB packed w1; reused as outP (37.7MB) after G1
    float* outP = (float*)p;                p += (size_t)EEXP * FDIM * DDIM * 2;
    char* w2bp = p;                         p += (size_t)EEXP * DDIM * FDIM * 2;   // 64 MB
    unsigned short* xb = (unsigned short*)p; p += (size_t)S_TOK * DDIM * 2;        //  8 MB
    char* xg  = p;                          p += (size_t)(PCAP / 128) * 32 * 8192;  // 18.9 MB
    char* hAp = p;                          p += (size_t)(PCAP / 128) * 128 * 8192; // 75.5 MB
    int*   topk_e      = (int*)p;           p += S_TOK * 2 * 4;
    float* topk_g      = (float*)p;         p += S_TOK * 2 * 4;
    int*   pos_of      = (int*)p;           p += S_TOK * 2 * 4;
    int*   arena_token = (int*)p;           p += PCAP * 4;
    int*   counts      = (int*)p;           p += 64;
    int*   rankctr     = (int*)p;           p += 64;
    int*   basep       = (int*)p;           p += 64;
    (void)ws_size; (void)in_sizes; (void)n_in; (void)out_size;

    zero_k<<<1, 64, 0, stream>>>(counts, 48);

    cvt_w1_packed<<<4096, 256, 0, stream>>>(w1, w1bp);
    cvt_w2_packed<<<4096, 256, 0, stream>>>(w2, w2bp);

    router_k<<<S_TOK, 64, 0, stream>>>(x, gate_w, xb, topk_e, topk_g, counts);
    scan_k<<<1, 1, 0, stream>>>(counts, basep);
    scatter_k<<<S_TOK / 256, 256, 0, stream>>>(topk_e, rankctr, basep, arena_token, pos_of);
    gather_k<<<PCAP * 128 / 256, 256, 0, stream>>>(xb, arena_token, counts, basep, xg);

    // GEMM1: A=xg packed (ktiles=32), B=w1bp (ntiles=16), out=hAp packed.
    // grid = 16 * 32 * 8 = 4096 (div 8).
    moe_gemm<1><<<dim3(16 * 32 * EEXP), 512, 0, stream>>>(
        xg, w1bp, b1, hAp, nullptr, counts, basep, 32, FDIM, 16, 32);
    // GEMM2: A=hAp packed (ktiles=128), B=w2bp (ntiles=4), out=outP fp32 (w1bp region).
    // grid = 4 * 32 * 8 = 1024 (div 8).
    moe_gemm<2><<<dim3(4 * 32 * EEXP), 512, 0, stream>>>(
        hAp, w2bp, nullptr, nullptr, outP, counts, basep, 128, DDIM, 4, 32);

    combine_k<<<S_TOK * DDIM / 4 / 256, 256, 0, stream>>>(
        outP, b2, topk_e, topk_g, pos_of, (float*)d_out);
}